// Round 16
// baseline (135.437 us; speedup 1.0000x reference)
//
#include <hip/hip_runtime.h>

#define MDIM 2048   // B
#define KD   2560   // HEAD
#define NHID 2048   // N_HID
#define INF  512
#define NS   40     // K-tiles of 64

typedef __attribute__((ext_vector_type(4))) float f32x4;
typedef __attribute__((ext_vector_type(8))) short short8;
typedef __attribute__((ext_vector_type(8))) unsigned short ushort8v;
typedef __attribute__((ext_vector_type(4))) unsigned short ushort4v;

#define AS1 __attribute__((address_space(1)))
#define AS3 __attribute__((address_space(3)))

__device__ __forceinline__ unsigned short f2bf(float f) {
    unsigned u = __float_as_uint(f);
    u += 0x7fffu + ((u >> 16) & 1u);
    return (unsigned short)(u >> 16);
}

// ---------------- merged prep: xc (blocks 0..2559) + Wm (blocks 2560..7679) ----------------
#define XCB 2560
__global__ void prep_all(const float* __restrict__ x, const float* __restrict__ h,
                         unsigned short* __restrict__ xc,
                         const float* __restrict__ Wg, const float* __restrict__ Wh,
                         const float* __restrict__ Wfg, const float* __restrict__ Wfh,
                         const float* __restrict__ Wp, const float* __restrict__ mask,
                         unsigned short* __restrict__ Wm) {
    if (blockIdx.x < XCB) {
        int idx = blockIdx.x * 256 + threadIdx.x;
        int e = idx * 8;
        int b = e / KD;
        int c = e - b * KD;
        const float* src = (c < INF) ? (x + (size_t)b * INF + c)
                                     : (h + (size_t)b * NHID + (c - INF));
        float4 v0 = *(const float4*)src;
        float4 v1 = *(const float4*)(src + 4);
        ushort8v o;
        o[0] = f2bf(v0.x); o[1] = f2bf(v0.y); o[2] = f2bf(v0.z); o[3] = f2bf(v0.w);
        o[4] = f2bf(v1.x); o[5] = f2bf(v1.y); o[6] = f2bf(v1.z); o[7] = f2bf(v1.w);
        *(ushort8v*)(xc + e) = o;
    } else {
        int idx = (blockIdx.x - XCB) * 256 + threadIdx.x;
        size_t e = (size_t)idx * 4;
        const size_t PL = (size_t)NHID * KD;
        int col = (int)(e % KD);
        float4 m;
        if (col < INF) m = *(const float4*)(mask + e);
        else           m = make_float4(1.f, 1.f, 1.f, 1.f);
        const float* Ws[5] = {Wg, Wh, Wfg, Wfh, Wp};
        #pragma unroll
        for (int k = 0; k < 5; ++k) {
            float4 w = *(const float4*)(Ws[k] + e);
            ushort4v o;
            o[0] = f2bf(w.x * m.x); o[1] = f2bf(w.y * m.y);
            o[2] = f2bf(w.z * m.z); o[3] = f2bf(w.w * m.w);
            *(ushort4v*)(Wm + k * PL + e) = o;
        }
    }
}

// ---------------- fused GEMM + epilogue: R15 + early-staging (drain de-stall) ----------------
// R15 structure unchanged: 256x64x5 tile, 8 waves (2M x 4N), 16x16x32 MFMA,
// acc[8][5], minimal reads (26 b128/wave/tile), plane-major B for in-register
// epilogue, swizzle K(r)=r&7, 4 phases x {reads; stage -> bar -> setprio MFMA
// -> bar}, one vmcnt(0)/tile.
// ONLY change: staging issue order. P0 issues ALL 5 SB (B streams from L3,
// ~400-600 cyc latency), P1 issues ALL 4 SA (A is L2-resident, fast), P2/P3
// issue nothing. At the P3-end drain the youngest load is ~2 phases (~1300
// cyc) old -> vmcnt(0) is near-free instead of stalling on P2-issued B ops.
#define MFMA16(d, va, vb) d = __builtin_amdgcn_mfma_f32_16x16x32_bf16(va, vb, d, 0, 0, 0)

__global__ __launch_bounds__(512, 2) void gemm_fused(
    const unsigned short* __restrict__ A,
    const unsigned short* __restrict__ Bm,
    const float* __restrict__ bg, const float* __restrict__ bh,
    const float* __restrict__ bfg, const float* __restrict__ bfh,
    const float* __restrict__ bp,
    float* __restrict__ out) {
    __shared__ unsigned short lsA[2][256 * 64];   // 64 KB
    __shared__ unsigned short lsB[2][320 * 64];   // 80 KB

    const int tid  = threadIdx.x;
    const int lane = tid & 63;
    const int w    = tid >> 6;       // 0..7
    const int wm   = w >> 2;         // 0..1  (M waves)
    const int wn   = w & 3;          // 0..3  (N col-quarter)
    const int lr   = lane & 15;
    const int kq   = lane >> 4;      // 0..3
    const int l7   = lane & 7;
    const int m0   = blockIdx.y * 256;
    const int n0c  = blockIdx.x * 64;

    const unsigned short* gA = A + (size_t)m0 * KD;
    // staging: 8 rows x 8 slots per instr; stored key K(r) = r&7
    const int soff = (lane >> 3) * KD + (((lane & 7) ^ (lane >> 3)) << 3);
    const int ar0 = (w >> 2) * 128 + (w & 3) * 8;  // + 32*j, j=0..3
    const int br0 = (w >> 1) * 80 + (w & 1) * 8;   // + 16*j, j=0..4

#define SA(j, t, b) __builtin_amdgcn_global_load_lds( \
        (const AS1 unsigned int*)(gA + (size_t)(ar0 + 32 * (j)) * KD + (t) * 64 + soff), \
        (AS3 unsigned int*)(&lsA[b][(ar0 + 32 * (j)) * 64]), 16, 0, 0)
#define SB(j, t, b) do { \
        const int r0_ = br0 + 16 * (j); \
        const int grow_ = (r0_ >> 6) * NHID + n0c + (r0_ & 63); \
        __builtin_amdgcn_global_load_lds( \
            (const AS1 unsigned int*)(Bm + (size_t)grow_ * KD + (t) * 64 + soff), \
            (AS3 unsigned int*)(&lsB[b][r0_ * 64]), 16, 0, 0); \
    } while (0)

    // reads: row key = row&7 = l7 (all read-row strides are multiples of 8)
    const int c0 = ((0 + kq) ^ l7) << 3;   // k-half 0 (ushort offset)
    const int c1 = ((4 + kq) ^ l7) << 3;   // k-half 1
    const int arow  = wm * 128 + lr;       // + 16*m
    const int browb = wn * 16 + lr;        // + 64*p (plane-major)

#define LDA(b, m, cs) (*(const short8*)&lsA[b][(arow + 16 * (m)) * 64 + (cs)])
#define LDB(b, p, cs) (*(const short8*)&lsB[b][((p) * 64 + browb) * 64 + (cs)])

#define PBAR() do { __builtin_amdgcn_s_barrier(); \
                    __builtin_amdgcn_sched_barrier(0); } while (0)

    f32x4 acc[8][5] = {};

    // prologue: stage kt=0 into buf 0
    SA(0, 0, 0); SA(1, 0, 0); SA(2, 0, 0); SA(3, 0, 0);
    SB(0, 0, 0); SB(1, 0, 0); SB(2, 0, 0); SB(3, 0, 0); SB(4, 0, 0);
    asm volatile("s_waitcnt vmcnt(0)" ::: "memory");
    __builtin_amdgcn_s_barrier();

    for (int kt = 0; kt < NS; ++kt) {
        const int bc = kt & 1, bo = bc ^ 1;
        const bool st = (kt + 1 < NS);
        short8 aL[4], aH[4], b0[5], b1[5];

        // ---- P0: M 0-3, K-half 0; stage ALL B(kt+1) (slow L3 path first) ----
        #pragma unroll
        for (int m = 0; m < 4; ++m) aL[m] = LDA(bc, m, c0);
        #pragma unroll
        for (int n = 0; n < 5; ++n) b0[n] = LDB(bc, n, c0);
        if (st) { SB(0, kt + 1, bo); SB(1, kt + 1, bo); SB(2, kt + 1, bo);
                  SB(3, kt + 1, bo); SB(4, kt + 1, bo); }
        PBAR();
        __builtin_amdgcn_s_setprio(1);
        #pragma unroll
        for (int m = 0; m < 4; ++m)
            #pragma unroll
            for (int n = 0; n < 5; ++n) MFMA16(acc[m][n], aL[m], b0[n]);
        __builtin_amdgcn_s_setprio(0);
        PBAR();

        // ---- P1: M 0-3, K-half 1; stage ALL A(kt+1) (fast L2 path) ----
        #pragma unroll
        for (int m = 0; m < 4; ++m) aL[m] = LDA(bc, m, c1);
        #pragma unroll
        for (int n = 0; n < 5; ++n) b1[n] = LDB(bc, n, c1);
        if (st) { SA(0, kt + 1, bo); SA(1, kt + 1, bo);
                  SA(2, kt + 1, bo); SA(3, kt + 1, bo); }
        PBAR();
        __builtin_amdgcn_s_setprio(1);
        #pragma unroll
        for (int m = 0; m < 4; ++m)
            #pragma unroll
            for (int n = 0; n < 5; ++n) MFMA16(acc[m][n], aL[m], b1[n]);
        __builtin_amdgcn_s_setprio(0);
        PBAR();

        // ---- P2: M 4-7, K-half 0 (b0 held live; no staging) ----
        #pragma unroll
        for (int m = 0; m < 4; ++m) aH[m] = LDA(bc, 4 + m, c0);
        PBAR();
        __builtin_amdgcn_s_setprio(1);
        #pragma unroll
        for (int m = 0; m < 4; ++m)
            #pragma unroll
            for (int n = 0; n < 5; ++n) MFMA16(acc[4 + m][n], aH[m], b0[n]);
        __builtin_amdgcn_s_setprio(0);
        PBAR();

        // ---- P3: M 4-7, K-half 1 (b1 held live; no staging) ----
        #pragma unroll
        for (int m = 0; m < 4; ++m) aH[m] = LDA(bc, 4 + m, c1);
        PBAR();
        __builtin_amdgcn_s_setprio(1);
        #pragma unroll
        for (int m = 0; m < 4; ++m)
            #pragma unroll
            for (int n = 0; n < 5; ++n) MFMA16(acc[4 + m][n], aH[m], b1[n]);
        __builtin_amdgcn_s_setprio(0);
        // flip gate: youngest staged op is ~2 phases (~1300 cyc) old -> ~free
        asm volatile("s_waitcnt vmcnt(0)" ::: "memory");
        __builtin_amdgcn_s_barrier();
    }

    // ---- fused epilogue (16x16 C/D: col = lane&15, row = m*16 + kq*4 + j) ----
    const int col = n0c + wn * 16 + lr;
    const float bgv = bg[col];
    const float bhv = bh[col];
    const float bfv = bfg[col] + bfh[col];
    const float bpv = bp[col];
    const size_t PL = (size_t)MDIM * NHID;
    #pragma unroll
    for (int m = 0; m < 8; ++m) {
        #pragma unroll
        for (int j = 0; j < 4; ++j) {
            const int row = m0 + wm * 128 + m * 16 + kq * 4 + j;
            float gx = acc[m][0][j] + bgv;
            float hx = acc[m][1][j] + bhv;
            float sx = acc[m][2][j] + acc[m][3][j] + bfv;
            float tg = __expf(-2.0f * fabsf(gx));
            float g  = __builtin_copysignf((1.0f - tg) / (1.0f + tg), gx);
            float th = __expf(-2.0f * fabsf(hx));
            float hh = __builtin_copysignf((1.0f - th) / (1.0f + th), hx);
            float gate = 1.0f / (1.0f + __expf(-sx));
            float nh = g * (1.0f - gate) + gate * hh;
            float y  = acc[m][4][j] + bpv + nh;
            out[(size_t)row * NHID + col]      = y;
            out[PL + (size_t)row * NHID + col] = nh;
        }
    }
#undef SA
#undef SB
#undef LDA
#undef LDB
#undef PBAR
}

extern "C" void kernel_launch(void* const* d_in, const int* in_sizes, int n_in,
                              void* d_out, int out_size, void* d_ws, size_t ws_size,
                              hipStream_t stream) {
    const float* x      = (const float*)d_in[0];
    const float* hidden = (const float*)d_in[1];
    const float* mask   = (const float*)d_in[2];
    const float* Wg     = (const float*)d_in[3];
    const float* bg     = (const float*)d_in[4];
    const float* Wh     = (const float*)d_in[5];
    const float* bh     = (const float*)d_in[6];
    const float* Wfg    = (const float*)d_in[7];
    const float* bfg    = (const float*)d_in[8];
    const float* Wfh    = (const float*)d_in[9];
    const float* bfh    = (const float*)d_in[10];
    const float* Wp     = (const float*)d_in[11];
    const float* bp     = (const float*)d_in[12];
    float* out = (float*)d_out;

    const size_t need = (size_t)MDIM * KD * 2 + (size_t)5 * NHID * KD * 2;
    if (ws_size < need) return;

    unsigned short* xc = (unsigned short*)d_ws;
    unsigned short* Wm = xc + (size_t)MDIM * KD;

    prep_all<<<XCB + NHID * KD / 4 / 256, 256, 0, stream>>>(
        x, hidden, xc, Wg, Wh, Wfg, Wfh, Wp, mask, Wm);
    dim3 grid(NHID / 64, MDIM / 256);
    gemm_fused<<<grid, 512, 0, stream>>>(xc, Wm, bg, bh, bfg, bfh, bp, out);
}